// Round 4
// baseline (1193.927 us; speedup 1.0000x reference)
//
#include <hip/hip_runtime.h>

#define B_ 1024
#define S_ 128
#define E_ 256
#define H_ 8
#define D_ 64
#define HD_ 512

typedef short s16x8 __attribute__((ext_vector_type(8)));   // 8 bf16 (guide §3)
typedef float f32x4 __attribute__((ext_vector_type(4)));
typedef unsigned int u32x4 __attribute__((ext_vector_type(4)));
typedef unsigned short u16;
typedef unsigned int u32;

struct U16x8 { u16 v[8]; };

__device__ __forceinline__ u16 f2bf(float f) {
  u32 u = __float_as_uint(f);
  u += 0x7FFFu + ((u >> 16) & 1u);   // round-to-nearest-even
  return (u16)(u >> 16);
}

// ---------------------------------------------------------------------------
// Dtype probe: decide whether inputs are packed bf16 or float32.
// For bf16-packed X, the low u16 of each u32 word is a bf16 of N(0,1): its
// exponent field (bits 14:7) sits in [97,159] essentially always. For f32 X,
// bits 14:7 are mantissa bits: uniform, in-band ~25%. 256 samples -> >9 sigma.
// flag[0] = 1 (bf16) or 0 (f32), recomputed every launch (graph-safe).
// ---------------------------------------------------------------------------
__global__ __launch_bounds__(256) void probe_dtype(const u32* __restrict__ x,
                                                   u32* __restrict__ flag) {
  __shared__ int cnt;
  if (threadIdx.x == 0) cnt = 0;
  __syncthreads();
  u32 w = x[threadIdx.x];
  u32 e = (w >> 7) & 0xFFu;
  if (e > 96u && e < 160u) atomicAdd(&cnt, 1);
  __syncthreads();
  if (threadIdx.x == 0) flag[0] = (cnt > 128) ? 1u : 0u;
}

// ---------------------------------------------------------------------------
// Repack the four (E x HD) weights into bf16 MFMA B-fragment order:
// WF[(((w*8+h)*8+ks)*4+tc)*64+lane][j] = W_w[ks*32+(lane>>4)*8+j][h*64+tc*16+(lane&15)]
// ---------------------------------------------------------------------------
__global__ __launch_bounds__(256) void repack_w(
    const void* __restrict__ wqv, const void* __restrict__ wkv,
    const void* __restrict__ wvv, const void* __restrict__ wrv,
    const u32* __restrict__ flag, u16* __restrict__ wf) {
  bool isbf = (flag[0] != 0u);
  int t = blockIdx.x * 256 + threadIdx.x;   // 65536 threads total
  int lane = t & 63;
  int tc   = (t >> 6) & 3;
  int ks   = (t >> 8) & 7;
  int h    = (t >> 11) & 7;
  int w    = (t >> 14) & 3;
  const void* srcv = (w == 0) ? wqv : (w == 1) ? wkv : (w == 2) ? wvv : wrv;
  int n  = h * D_ + tc * 16 + (lane & 15);
  int e0 = ks * 32 + (lane >> 4) * 8;
  U16x8 tmp;
  if (isbf) {
    const u16* s = (const u16*)srcv;
#pragma unroll
    for (int j = 0; j < 8; ++j) tmp.v[j] = s[(e0 + j) * HD_ + n];
  } else {
    const float* s = (const float*)srcv;
#pragma unroll
    for (int j = 0; j < 8; ++j) tmp.v[j] = f2bf(s[(e0 + j) * HD_ + n]);
  }
  *(u32x4*)(wf + (size_t)t * 8) = *(const u32x4*)tmp.v;
}

// Projection via repacked fragments: one dwordx4 per B-frag.
__device__ __forceinline__ void proj4_wf(const u32x4* __restrict__ wf4lane, int base8,
                                         const s16x8 xfrag[8], f32x4 acc[4]) {
#pragma unroll
  for (int tc = 0; tc < 4; ++tc) acc[tc] = (f32x4){0.f, 0.f, 0.f, 0.f};
#pragma unroll
  for (int ks = 0; ks < 8; ++ks) {
#pragma unroll
    for (int tc = 0; tc < 4; ++tc) {
      u32x4 raw = wf4lane[((base8 * 8 + ks) * 4 + tc) * 64];
      s16x8 bfr = *(const s16x8*)&raw;
      acc[tc] = __builtin_amdgcn_mfma_f32_16x16x32_bf16(xfrag[ks], bfr, acc[tc], 0, 0, 0);
    }
  }
}

// Fallback (ws too small for WF): gather B-frags from the original layout.
__device__ __forceinline__ void proj4_direct(const void* __restrict__ srcv, bool isbf,
                                             int h, int lane, const s16x8 xfrag[8],
                                             f32x4 acc[4]) {
#pragma unroll
  for (int tc = 0; tc < 4; ++tc) acc[tc] = (f32x4){0.f, 0.f, 0.f, 0.f};
  int e8 = (lane >> 4) * 8;
  int nc = h * D_ + (lane & 15);
#pragma unroll
  for (int ks = 0; ks < 8; ++ks) {
#pragma unroll
    for (int tc = 0; tc < 4; ++tc) {
      U16x8 tmp;
      if (isbf) {
        const u16* s = (const u16*)srcv;
#pragma unroll
        for (int j = 0; j < 8; ++j) tmp.v[j] = s[(ks * 32 + e8 + j) * HD_ + nc + tc * 16];
      } else {
        const float* s = (const float*)srcv;
#pragma unroll
        for (int j = 0; j < 8; ++j) tmp.v[j] = f2bf(s[(ks * 32 + e8 + j) * HD_ + nc + tc * 16]);
      }
      s16x8 bfr = *(const s16x8*)tmp.v;
      acc[tc] = __builtin_amdgcn_mfma_f32_16x16x32_bf16(xfrag[ks], bfr, acc[tc], 0, 0, 0);
    }
  }
}

// Scatter projection C-frags (row=quad*4+r, col=tc*16+col) into A-frag-major
// (Q) / B-frag-major (K) LDS layout — same index formula for both.
__device__ __forceinline__ void scatter_qk(u16* dst, int w, int quad, int col,
                                           const f32x4 acc[4]) {
#pragma unroll
  for (int tc = 0; tc < 4; ++tc) {
    int ks2 = tc >> 1;
    int q2  = (tc & 1) * 2 + (col >> 3);
#pragma unroll
    for (int r = 0; r < 4; ++r)
      dst[(((w * 2 + ks2) * 64) + q2 * 16 + quad * 4 + r) * 8 + (col & 7)] =
          f2bf(acc[tc][r]);
  }
}

// V goes to B-frag-major for O = P@V (k = s', n = d).
__device__ __forceinline__ void scatter_v(u16* Vf, int w, int quad, int col,
                                          const f32x4 acc[4]) {
#pragma unroll
  for (int tc = 0; tc < 4; ++tc)
#pragma unroll
    for (int r = 0; r < 4; ++r) {
      int srow = quad * 4 + r;
      int q2   = (w & 1) * 2 + (srow >> 3);
      Vf[((((w >> 1) * 4 + tc) * 64) + q2 * 16 + col) * 8 + (srow & 7)] =
          f2bf(acc[tc][r]);
    }
}

// ---------------------------------------------------------------------------
// Fused MHA: one workgroup per batch, 8 waves, head loop inside.
// LDS (56 KiB): Qf 16K | Kf 16K | Vf 16K | Pf 8K (per-wave single buffer)
// ---------------------------------------------------------------------------
__global__ __launch_bounds__(512) void mha_fused(
    const void* __restrict__ Xv, const u16* __restrict__ WF,
    const void* __restrict__ wqv, const void* __restrict__ wkv,
    const void* __restrict__ wvv, const void* __restrict__ wrv,
    void* __restrict__ outv, const u32* __restrict__ flag, int useWF) {
  __shared__ __align__(16) u16 smem[28672];
  u16* Qf = smem;            // 8192 elems
  u16* Kf = smem + 8192;     // 8192
  u16* Vf = smem + 16384;    // 8192
  u16* Pf = smem + 24576;    // 4096: [wave][512]

  const bool isbf = (flag[0] != 0u);
  const int tid  = threadIdx.x;
  const int w    = tid >> 6;     // wave id: owns rows [16w, 16w+16)
  const int lane = tid & 63;
  const int quad = lane >> 4;
  const int col  = lane & 15;
  const int b    = blockIdx.x;

  // ---- stage X[b] through LDS (two halves) into per-wave A-frags ----
  s16x8 xfrag[8];
  {
    u32x4* xs = (u32x4*)smem;
#pragma unroll
    for (int half = 0; half < 2; ++half) {
      int cbase = half * 2048;
#pragma unroll
      for (int k = 0; k < 4; ++k) {
        int c  = cbase + tid + k * 512;       // 8-element chunk id
        int s  = c >> 5;                      // row 0..127
        int e0 = (c & 31) * 8;                // elem base within row
        U16x8 tmp;
        if (isbf) {
          const u32x4* xg = (const u32x4*)Xv + (size_t)b * 4096;
          u32x4 raw = xg[c];
          tmp = *(const U16x8*)&raw;
        } else {
          const f32x4* xg = (const f32x4*)Xv + (size_t)b * 8192;
          f32x4 lo = xg[2 * c], hi = xg[2 * c + 1];
#pragma unroll
          for (int j = 0; j < 4; ++j) { tmp.v[j] = f2bf(lo[j]); tmp.v[4 + j] = f2bf(hi[j]); }
        }
        xs[(((s >> 4) & 3) * 8 + (e0 >> 5)) * 64 + ((e0 >> 3) & 3) * 16 + (s & 15)] =
            *(const u32x4*)tmp.v;
      }
      __syncthreads();
      if ((w >> 2) == half) {
        int trl = w & 3;
#pragma unroll
        for (int ks = 0; ks < 8; ++ks) {
          u32x4 raw = xs[(trl * 8 + ks) * 64 + lane];
          xfrag[ks] = *(const s16x8*)&raw;
        }
      }
      __syncthreads();
    }
  }

  const u32x4* wf4 = ((const u32x4*)WF) + lane;

  for (int h = 0; h < H_; ++h) {
    // ---- projections: Q, K, V to LDS; R stays in registers ----
    f32x4 acc[4], ra[4];
    if (useWF) proj4_wf(wf4, 0 * 8 + h, xfrag, acc);
    else       proj4_direct(wqv, isbf, h, lane, xfrag, acc);
    scatter_qk(Qf, w, quad, col, acc);
    if (useWF) proj4_wf(wf4, 1 * 8 + h, xfrag, acc);
    else       proj4_direct(wkv, isbf, h, lane, xfrag, acc);
    scatter_qk(Kf, w, quad, col, acc);
    if (useWF) proj4_wf(wf4, 2 * 8 + h, xfrag, acc);
    else       proj4_direct(wvv, isbf, h, lane, xfrag, acc);
    scatter_v(Vf, w, quad, col, acc);
    if (useWF) proj4_wf(wf4, 3 * 8 + h, xfrag, ra);
    else       proj4_direct(wrv, isbf, h, lane, xfrag, ra);
    __syncthreads();

    // ---- S = Q K^T : this wave's 16x128 strip (8 tiles, K=64) ----
    s16x8 aq[2];
#pragma unroll
    for (int k2 = 0; k2 < 2; ++k2)
      aq[k2] = *(const s16x8*)(Qf + ((w * 2 + k2) * 64 + lane) * 8);
    f32x4 sacc[8];
#pragma unroll
    for (int tS = 0; tS < 8; ++tS) {
      sacc[tS] = (f32x4){0.f, 0.f, 0.f, 0.f};
#pragma unroll
      for (int k2 = 0; k2 < 2; ++k2) {
        s16x8 bk = *(const s16x8*)(Kf + ((tS * 2 + k2) * 64 + lane) * 8);
        sacc[tS] = __builtin_amdgcn_mfma_f32_16x16x32_bf16(aq[k2], bk, sacc[tS], 0, 0, 0);
      }
    }

    // ---- row softmax (row quad*4+r lives in the 16 lanes of this quad) ----
    float rmax[4], linv[4];
#pragma unroll
    for (int r = 0; r < 4; ++r) {
      float m = sacc[0][r];
#pragma unroll
      for (int tS = 1; tS < 8; ++tS) m = fmaxf(m, sacc[tS][r]);
      m = fmaxf(m, __shfl_xor(m, 1));
      m = fmaxf(m, __shfl_xor(m, 2));
      m = fmaxf(m, __shfl_xor(m, 4));
      m = fmaxf(m, __shfl_xor(m, 8));
      rmax[r] = m;
    }
#pragma unroll
    for (int tS = 0; tS < 8; ++tS)
#pragma unroll
      for (int r = 0; r < 4; ++r) sacc[tS][r] = __expf(sacc[tS][r] - rmax[r]);
#pragma unroll
    for (int r = 0; r < 4; ++r) {
      float l = sacc[0][r];
#pragma unroll
      for (int tS = 1; tS < 8; ++tS) l += sacc[tS][r];
      l += __shfl_xor(l, 1);
      l += __shfl_xor(l, 2);
      l += __shfl_xor(l, 4);
      l += __shfl_xor(l, 8);
      linv[r] = 1.0f / l;
    }

    // ---- O = P V, P chunked through per-wave LDS buffer (A-frag layout) ----
    f32x4 oacc[4];
#pragma unroll
    for (int tc = 0; tc < 4; ++tc) oacc[tc] = (f32x4){0.f, 0.f, 0.f, 0.f};
    u16* Pw = Pf + w * 512;                  // in-bounds: max 7*512+511 = 4095
#pragma unroll
    for (int ko = 0; ko < 4; ++ko) {
#pragma unroll
      for (int hp = 0; hp < 2; ++hp) {
        int tS = ko * 2 + hp;
        int q2 = hp * 2 + (col >> 3);
#pragma unroll
        for (int r = 0; r < 4; ++r)
          Pw[(q2 * 16 + quad * 4 + r) * 8 + (col & 7)] = f2bf(sacc[tS][r]);
      }
      __threadfence_block();    // drain LDS writes before cross-lane reads
      s16x8 ap = *(const s16x8*)(Pw + lane * 8);
#pragma unroll
      for (int tc = 0; tc < 4; ++tc) {
        s16x8 bv = *(const s16x8*)(Vf + ((ko * 4 + tc) * 64 + lane) * 8);
        oacc[tc] = __builtin_amdgcn_mfma_f32_16x16x32_bf16(ap, bv, oacc[tc], 0, 0, 0);
      }
      __threadfence_block();    // reads complete before next iter overwrites
    }

    // ---- epilogue: 1/l scaling + residual + ReLU, dtype-matched store ----
#pragma unroll
    for (int tc = 0; tc < 4; ++tc)
#pragma unroll
      for (int r = 0; r < 4; ++r) {
        float v = oacc[tc][r] * linv[r] + ra[tc][r];
        v = fmaxf(v, 0.f);
        int s = w * 16 + quad * 4 + r;
        size_t idx = ((size_t)b * S_ + s) * HD_ + h * D_ + tc * 16 + col;
        if (isbf) ((u16*)outv)[idx] = f2bf(v);
        else      ((float*)outv)[idx] = v;
      }
    __syncthreads();   // protect Qf/Kf/Vf before next head overwrites
  }
}

extern "C" void kernel_launch(void* const* d_in, const int* in_sizes, int n_in,
                              void* d_out, int out_size, void* d_ws, size_t ws_size,
                              hipStream_t stream) {
  const void* X  = d_in[0];
  const void* wq = d_in[1];
  const void* wk = d_in[2];
  const void* wv = d_in[3];
  const void* wr = d_in[4];

  u32* flag = (u32*)d_ws;                       // 4 B flag at ws offset 0
  u16* wf   = (u16*)((char*)d_ws + 4096);       // 1 MiB fragment cache
  int useWF = (ws_size >= (size_t)(1u << 20) + 4096) ? 1 : 0;

  probe_dtype<<<dim3(1), dim3(256), 0, stream>>>((const u32*)X, flag);
  if (useWF)
    repack_w<<<dim3(256), dim3(256), 0, stream>>>(wq, wk, wv, wr, flag, wf);
  mha_fused<<<dim3(B_), dim3(512), 0, stream>>>(X, wf, wq, wk, wv, wr, d_out, flag, useWF);
}